// Round 10
// baseline (458.761 us; speedup 1.0000x reference)
//
#include <hip/hip_runtime.h>
#include <math.h>

#define N_NODES 50000
#define N_EDGES 800000
#define F_IN 64
#define D 128
#define NLAYER 3
#define B_GRAPHS 8
#define GB 32               // nodes per block (4 waves; staging 8 nodes/wave; MFMA tiles 2x2)
#define NPW 8               // nodes per wave (staging)
#define NBLK ((N_NODES + GB - 1) / GB)            // 1563 (last block partial)
#define SCAN_B 512
#define NPART ((N_NODES + SCAN_B - 1) / SCAN_B)   // 98
#define AGP 136             // agg LDS row stride in ushorts (128 + 8 pad -> 16B-aligned rows)

typedef float f32x4 __attribute__((ext_vector_type(4)));
typedef short bf16x8 __attribute__((ext_vector_type(8)));

__device__ __forceinline__ float gelu_exact(float x) {
    return 0.5f * x * (1.0f + erff(x * 0.7071067811865476f));
}

// fp32 -> bf16 round-to-nearest-even
__device__ __forceinline__ unsigned short f2bf(float f) {
    unsigned int u = __float_as_uint(f);
    u = (u + 0x7fffu + ((u >> 16) & 1u)) >> 16;
    return (unsigned short)u;
}
__device__ __forceinline__ float bf2f(unsigned short u) {
    return __uint_as_float((unsigned int)u << 16);
}

// ---------------- CSR build ----------------

__global__ void degree_kernel(const int* __restrict__ dst, int* __restrict__ deg) {
    int e = blockIdx.x * blockDim.x + threadIdx.x;
    if (e < N_EDGES) atomicAdd(&deg[dst[e]], 1);
}

__global__ __launch_bounds__(SCAN_B) void scan_partials_kernel(const int* __restrict__ deg,
                                                               int* __restrict__ partials) {
    __shared__ int wsum[8];
    int tid = threadIdx.x;
    int lane = tid & 63, wave = tid >> 6;
    int i = blockIdx.x * SCAN_B + tid;
    int v = (i < N_NODES) ? deg[i] : 0;
    #pragma unroll
    for (int o = 32; o >= 1; o >>= 1) v += __shfl_xor(v, o);
    if (lane == 0) wsum[wave] = v;
    __syncthreads();
    if (tid == 0) {
        int t = 0;
        #pragma unroll
        for (int w = 0; w < 8; ++w) t += wsum[w];
        partials[blockIdx.x] = t;
    }
}

// apply: each block self-reduces the partial prefix (no separate offsets kernel)
__global__ __launch_bounds__(SCAN_B) void scan_apply_v2(const int* __restrict__ deg,
        const int* __restrict__ partials, int* __restrict__ row_ptr, int* __restrict__ cursor) {
    __shared__ int wsum[8];
    __shared__ int base_s;
    int tid = threadIdx.x;
    int lane = tid & 63, wave = tid >> 6;

    // block-wide sum of partials[0..bid)
    int b = 0;
    for (int i = tid; i < (int)blockIdx.x; i += SCAN_B) b += partials[i];
    #pragma unroll
    for (int o = 32; o >= 1; o >>= 1) b += __shfl_xor(b, o);
    if (lane == 0) wsum[wave] = b;
    __syncthreads();
    if (tid == 0) {
        int t = 0;
        #pragma unroll
        for (int w = 0; w < 8; ++w) t += wsum[w];
        base_s = t;
    }
    __syncthreads();
    int base = base_s;
    __syncthreads();

    if (blockIdx.x == 0) {
        // total -> row_ptr[N_NODES]
        int t = 0;
        for (int i = tid; i < NPART; i += SCAN_B) t += partials[i];
        #pragma unroll
        for (int o = 32; o >= 1; o >>= 1) t += __shfl_xor(t, o);
        if (lane == 0) wsum[wave] = t;
        __syncthreads();
        if (tid == 0) {
            int tt = 0;
            #pragma unroll
            for (int w = 0; w < 8; ++w) tt += wsum[w];
            row_ptr[N_NODES] = tt;
        }
        __syncthreads();
    }

    int i = blockIdx.x * SCAN_B + tid;
    int v = (i < N_NODES) ? deg[i] : 0;
    int x = v;
    #pragma unroll
    for (int o = 1; o < 64; o <<= 1) { int nb = __shfl_up(x, o); if (lane >= o) x += nb; }
    if (lane == 63) wsum[wave] = x;
    __syncthreads();
    int waveoff = 0;
    #pragma unroll
    for (int w = 0; w < 8; ++w) waveoff += (w < wave) ? wsum[w] : 0;
    int excl = base + waveoff + x - v;
    if (i < N_NODES) { row_ptr[i] = excl; cursor[i] = excl; }
}

__global__ void fill_kernel(const int* __restrict__ src, const int* __restrict__ dst,
                            int* __restrict__ cursor, int* __restrict__ csr) {
    int e = blockIdx.x * blockDim.x + threadIdx.x;
    if (e < N_EDGES) {
        int t = dst[e];
        int pos = atomicAdd(&cursor[t], 1);
        csr[pos] = src[e];
    }
}

// W prep: gnn_w -> wt bf16 [L][n=D][k=2D]; gate_w1 -> [n=D][k=D]; w_in -> [n=D][k=F_IN]
// block 0 also zeroes pooled (1024 floats)
#define WT_GNN (NLAYER * D * 2 * D)
#define WT_G1  (WT_GNN + D * D)
#define WT_ALL (WT_G1 + D * F_IN)
__global__ void wprep_kernel(const float* __restrict__ gnn_w, const float* __restrict__ gate_w1,
                             const float* __restrict__ w_in, unsigned short* __restrict__ wt,
                             float* __restrict__ pooled) {
    int idx = blockIdx.x * 256 + threadIdx.x;
    if (blockIdx.x == 0) {
        #pragma unroll
        for (int i = 0; i < 4; ++i) pooled[threadIdx.x + i * 256] = 0.f;
    }
    if (idx >= WT_ALL) return;
    if (idx < WT_GNN) {
        int l = idx / (D * 2 * D);
        int rem = idx - l * (D * 2 * D);
        int n = rem / (2 * D);
        int k = rem - n * (2 * D);
        wt[idx] = f2bf(gnn_w[(size_t)l * 2 * D * D + (size_t)k * D + n]);
    } else if (idx < WT_G1) {
        int rem = idx - WT_GNN;
        int n = rem / D;
        int k = rem - n * D;
        wt[idx] = f2bf(gate_w1[(size_t)k * D + n]);
    } else {
        int rem = idx - WT_G1;
        int n = rem / F_IN;
        int k = rem - n * F_IN;
        wt[idx] = f2bf(w_in[(size_t)k * D + n]);
    }
}

// ---------------- input proj v5: MFMA, x converted fp32->bf16 in-register ----------------

__global__ __launch_bounds__(256) void input_proj_v5(
        const float* __restrict__ x, const unsigned short* __restrict__ wti,
        const float* __restrict__ b, const float* __restrict__ gam,
        const float* __restrict__ bet, unsigned short* __restrict__ h16) {
    __shared__ float2 red[2][GB];
    int tid = threadIdx.x;
    int wave = tid >> 6, lane = tid & 63;
    int nblk0 = blockIdx.x * GB;
    int q = lane >> 4, c = lane & 15;
    int m0 = (wave >> 1) * 16;
    int n0 = (wave & 1) * 64;
    int mrow = nblk0 + m0 + c;
    int mclamp = (mrow < N_NODES) ? mrow : (N_NODES - 1);
    const float* xr = x + (size_t)mclamp * F_IN;

    f32x4 acc[4];
    #pragma unroll
    for (int t = 0; t < 4; ++t) {
        float bn = b[n0 + t * 16 + c];
        acc[t] = (f32x4){bn, bn, bn, bn};
    }
    #pragma unroll
    for (int kk = 0; kk < 2; ++kk) {
        float4 a0 = *(const float4*)&xr[kk * 32 + q * 8];
        float4 a1 = *(const float4*)&xr[kk * 32 + q * 8 + 4];
        bf16x8 av;
        av[0] = (short)f2bf(a0.x); av[1] = (short)f2bf(a0.y);
        av[2] = (short)f2bf(a0.z); av[3] = (short)f2bf(a0.w);
        av[4] = (short)f2bf(a1.x); av[5] = (short)f2bf(a1.y);
        av[6] = (short)f2bf(a1.z); av[7] = (short)f2bf(a1.w);
        #pragma unroll
        for (int t = 0; t < 4; ++t) {
            bf16x8 bv = *(const bf16x8*)&wti[(size_t)(n0 + t * 16 + c) * F_IN + kk * 32 + q * 8];
            acc[t] = __builtin_amdgcn_mfma_f32_16x16x32_bf16(av, bv, acc[t], 0, 0, 0);
        }
    }
    float s[4], sq[4];
    #pragma unroll
    for (int r = 0; r < 4; ++r) {
        s[r] = acc[0][r] + acc[1][r] + acc[2][r] + acc[3][r];
        sq[r] = acc[0][r] * acc[0][r] + acc[1][r] * acc[1][r]
              + acc[2][r] * acc[2][r] + acc[3][r] * acc[3][r];
    }
    #pragma unroll
    for (int o = 1; o <= 8; o <<= 1)
        #pragma unroll
        for (int r = 0; r < 4; ++r) { s[r] += __shfl_xor(s[r], o); sq[r] += __shfl_xor(sq[r], o); }
    if (c == 0) {
        #pragma unroll
        for (int r = 0; r < 4; ++r) red[wave & 1][m0 + q * 4 + r] = make_float2(s[r], sq[r]);
    }
    __syncthreads();
    float gv[4], bv2[4];
    #pragma unroll
    for (int t = 0; t < 4; ++t) {
        int nn = n0 + t * 16 + c;
        gv[t] = gam[nn]; bv2[t] = bet[nn];
    }
    #pragma unroll
    for (int r = 0; r < 4; ++r) {
        int m = m0 + q * 4 + r;
        int n = nblk0 + m;
        float2 p0 = red[0][m], p1 = red[1][m];
        float mean = (p0.x + p1.x) * (1.0f / D);
        float msq  = (p0.y + p1.y) * (1.0f / D);
        float istd = rsqrtf(msq - mean * mean + 1e-5f);
        if (n < N_NODES) {
            #pragma unroll
            for (int t = 0; t < 4; ++t) {
                int nn = n0 + t * 16 + c;
                float y = (acc[t][r] - mean) * istd * gv[t] + bv2[t];
                h16[(size_t)n * D + nn] = f2bf(gelu_exact(y));
            }
        }
    }
}

// ---------------- GNN layer v8: paired-node pipelined gather + MFMA ----------

__device__ __forceinline__ void acc_row(float acc[8], bf16x8 v) {
    #pragma unroll
    for (int i = 0; i < 8; ++i)
        acc[i] += __uint_as_float(((unsigned int)(unsigned short)v[i]) << 16);
}

template<int DO_GATE>
__global__ __launch_bounds__(256) void gnn_layer_v8(
        const unsigned short* __restrict__ h16_in, unsigned short* __restrict__ h16_out,
        float* __restrict__ hf_out,
        const int* __restrict__ csr, const int* __restrict__ rp,
        const unsigned short* __restrict__ wt,   // [n=D][k=2D] bf16
        const float* __restrict__ bias,
        const float* __restrict__ ln1g, const float* __restrict__ ln1b,
        const float* __restrict__ ln2g, const float* __restrict__ ln2b,
        int residual, int write_f32,
        const unsigned short* __restrict__ wtg,  // gate w1 [n=D][k=D] bf16 (DO_GATE)
        const float* __restrict__ gb1, const float* __restrict__ gw2,
        const float* __restrict__ gb2,
        float* __restrict__ logits, float2* __restrict__ gpart) {
    __shared__ int rps[GB + 1];
    __shared__ int eidx[GB][32];                // 4 KB
    __shared__ unsigned short aggb[GB][AGP];    // 8.7 KB (agg half; reused for gate staging)
    __shared__ float2 red1[2][GB];
    __shared__ float2 red2[2][GB];
    __shared__ float redg[2][GB];
    __shared__ float lg[GB];

    int tid = threadIdx.x;
    int wave = tid >> 6, lane = tid & 63;
    int nblk0 = blockIdx.x * GB;
    int gbase = wave * NPW;

    // phase 1: row_ptr slice -> LDS
    if (tid < GB + 1) {
        int n = nblk0 + tid;
        if (n > N_NODES) n = N_NODES;
        rps[tid] = rp[n];
    }
    __syncthreads();
    // phase 2: cooperative edge-index fill (clamped slots), one coalesced pass
    #pragma unroll
    for (int k2 = 0; k2 < 4; ++k2) {
        int f = tid + k2 * 256;
        int g = f >> 5, sl = f & 31;
        int beg = rps[g], end = rps[g + 1];
        int ee = beg + sl;
        int ci = (ee < end) ? ee : ((end > beg) ? (end - 1) : 0);
        eidx[g][sl] = csr[ci];
    }
    __syncthreads();

    // phase 3: gather, nodes in PAIRS for 16 outstanding row loads
    {
        int er = lane >> 4, dg = lane & 15;
        #pragma unroll
        for (int jj = 0; jj < NPW; jj += 2) {
            int gA = gbase + jj, gB2 = gbase + jj + 1;
            int begA = rps[gA], endA = rps[gA + 1];
            int begB = rps[gB2], endB = rps[gB2 + 1];
            int degA = endA - begA, degB = endB - begB;
            int idA[8], idB[8];
            #pragma unroll
            for (int t = 0; t < 8; ++t) { idA[t] = eidx[gA][er + 4 * t]; idB[t] = eidx[gB2][er + 4 * t]; }
            bf16x8 vA[8], vB[8];
            #pragma unroll
            for (int t = 0; t < 8; ++t)
                vA[t] = *(const bf16x8*)&h16_in[(size_t)idA[t] * D + dg * 8];
            #pragma unroll
            for (int t = 0; t < 8; ++t)
                vB[t] = *(const bf16x8*)&h16_in[(size_t)idB[t] * D + dg * 8];

            float accA[8], accB[8];
            #pragma unroll
            for (int i = 0; i < 8; ++i) { accA[i] = 0.f; accB[i] = 0.f; }
            #pragma unroll
            for (int t = 0; t < 8; ++t)
                if (begA + er + 4 * t < endA) acc_row(accA, vA[t]);
            #pragma unroll
            for (int t = 0; t < 8; ++t)
                if (begB + er + 4 * t < endB) acc_row(accB, vB[t]);
            if (degA > 32) {
                for (int ee = begA + er + 32; ee < endA; ee += 4) {
                    bf16x8 vv = *(const bf16x8*)&h16_in[(size_t)csr[ee] * D + dg * 8];
                    acc_row(accA, vv);
                }
            }
            if (degB > 32) {
                for (int ee = begB + er + 32; ee < endB; ee += 4) {
                    bf16x8 vv = *(const bf16x8*)&h16_in[(size_t)csr[ee] * D + dg * 8];
                    acc_row(accB, vv);
                }
            }
            #pragma unroll
            for (int i = 0; i < 8; ++i) {
                accA[i] += __shfl_xor(accA[i], 16);
                accA[i] += __shfl_xor(accA[i], 32);
                accB[i] += __shfl_xor(accB[i], 16);
                accB[i] += __shfl_xor(accB[i], 32);
            }
            float invA = 1.0f / fmaxf((float)degA, 1.0f);
            float invB = 1.0f / fmaxf((float)degB, 1.0f);
            if (er == 0) {
                bf16x8 oA, oB;
                #pragma unroll
                for (int i = 0; i < 8; ++i) {
                    oA[i] = (short)f2bf(accA[i] * invA);
                    oB[i] = (short)f2bf(accB[i] * invB);
                }
                *(bf16x8*)&aggb[gA][dg * 8] = oA;
                *(bf16x8*)&aggb[gB2][dg * 8] = oB;
            }
        }
    }
    __syncthreads();

    // ---- MFMA GEMM: wave tile = 16 nodes x 64 dims; K=256 (128 self global, 128 agg LDS)
    int q = lane >> 4, c = lane & 15;
    int m0 = (wave >> 1) * 16;
    int n0 = (wave & 1) * 64;
    int mrow = nblk0 + m0 + c;
    int mclamp = (mrow < N_NODES) ? mrow : (N_NODES - 1);
    const unsigned short* arow = h16_in + (size_t)mclamp * D;

    f32x4 acc[4];
    #pragma unroll
    for (int t = 0; t < 4; ++t) {
        float bn = bias[n0 + t * 16 + c];
        acc[t] = (f32x4){bn, bn, bn, bn};
    }
    #pragma unroll
    for (int kk = 0; kk < 4; ++kk) {
        bf16x8 av = *(const bf16x8*)&arow[kk * 32 + q * 8];
        #pragma unroll
        for (int t = 0; t < 4; ++t) {
            bf16x8 bv = *(const bf16x8*)&wt[(size_t)(n0 + t * 16 + c) * 256 + kk * 32 + q * 8];
            acc[t] = __builtin_amdgcn_mfma_f32_16x16x32_bf16(av, bv, acc[t], 0, 0, 0);
        }
    }
    #pragma unroll
    for (int kk = 0; kk < 4; ++kk) {
        bf16x8 av = *(const bf16x8*)&aggb[m0 + c][kk * 32 + q * 8];
        #pragma unroll
        for (int t = 0; t < 4; ++t) {
            bf16x8 bv = *(const bf16x8*)&wt[(size_t)(n0 + t * 16 + c) * 256 + 128 + kk * 32 + q * 8];
            acc[t] = __builtin_amdgcn_mfma_f32_16x16x32_bf16(av, bv, acc[t], 0, 0, 0);
        }
    }

    // ---- epilogue: gelu -> LN1 -> LN2 -> (gelu+residual) in C-layout
    float xv[4][4];
    #pragma unroll
    for (int t = 0; t < 4; ++t)
        #pragma unroll
        for (int r = 0; r < 4; ++r) xv[t][r] = gelu_exact(acc[t][r]);

    float s[4], sq[4];
    #pragma unroll
    for (int r = 0; r < 4; ++r) {
        s[r] = xv[0][r] + xv[1][r] + xv[2][r] + xv[3][r];
        sq[r] = xv[0][r] * xv[0][r] + xv[1][r] * xv[1][r] + xv[2][r] * xv[2][r] + xv[3][r] * xv[3][r];
    }
    #pragma unroll
    for (int o = 1; o <= 8; o <<= 1)
        #pragma unroll
        for (int r = 0; r < 4; ++r) { s[r] += __shfl_xor(s[r], o); sq[r] += __shfl_xor(sq[r], o); }
    int nh = wave & 1;
    if (c == 0) {
        #pragma unroll
        for (int r = 0; r < 4; ++r) red1[nh][m0 + q * 4 + r] = make_float2(s[r], sq[r]);
    }
    __syncthreads();

    float g1v[4], b1v[4], g2v[4], b2v[4];
    #pragma unroll
    for (int t = 0; t < 4; ++t) {
        int nn = n0 + t * 16 + c;
        g1v[t] = ln1g[nn]; b1v[t] = ln1b[nn];
        g2v[t] = ln2g[nn]; b2v[t] = ln2b[nn];
    }

    float y1[4][4];
    #pragma unroll
    for (int r = 0; r < 4; ++r) {
        int m = m0 + q * 4 + r;
        float2 p0 = red1[0][m], p1 = red1[1][m];
        float mean = (p0.x + p1.x) * (1.0f / D);
        float msq  = (p0.y + p1.y) * (1.0f / D);
        float istd = rsqrtf(msq - mean * mean + 1e-5f);
        #pragma unroll
        for (int t = 0; t < 4; ++t)
            y1[t][r] = (xv[t][r] - mean) * istd * g1v[t] + b1v[t];
    }

    #pragma unroll
    for (int r = 0; r < 4; ++r) {
        s[r] = y1[0][r] + y1[1][r] + y1[2][r] + y1[3][r];
        sq[r] = y1[0][r] * y1[0][r] + y1[1][r] * y1[1][r] + y1[2][r] * y1[2][r] + y1[3][r] * y1[3][r];
    }
    #pragma unroll
    for (int o = 1; o <= 8; o <<= 1)
        #pragma unroll
        for (int r = 0; r < 4; ++r) { s[r] += __shfl_xor(s[r], o); sq[r] += __shfl_xor(sq[r], o); }
    if (c == 0) {
        #pragma unroll
        for (int r = 0; r < 4; ++r) red2[nh][m0 + q * 4 + r] = make_float2(s[r], sq[r]);
    }
    __syncthreads();

    #pragma unroll
    for (int r = 0; r < 4; ++r) {
        int m = m0 + q * 4 + r;
        int n = nblk0 + m;
        float2 p0 = red2[0][m], p1 = red2[1][m];
        float mean = (p0.x + p1.x) * (1.0f / D);
        float msq  = (p0.y + p1.y) * (1.0f / D);
        float istd = rsqrtf(msq - mean * mean + 1e-5f);
        #pragma unroll
        for (int t = 0; t < 4; ++t) {
            int nn = n0 + t * 16 + c;
            float y2 = (y1[t][r] - mean) * istd * g2v[t] + b2v[t];
            float o = residual ? (gelu_exact(y2) + bf2f(h16_in[(size_t)n * D + nn])) : y2;
            if (n < N_NODES) {
                h16_out[(size_t)n * D + nn] = f2bf(o);
                if (write_f32) hf_out[(size_t)n * D + nn] = o;
            }
            if (DO_GATE) aggb[m][nn] = f2bf(o);   // gate staging (aggb free after GEMM)
        }
    }

    if (DO_GATE) {
        __syncthreads();
        f32x4 gacc[4];
        #pragma unroll
        for (int t = 0; t < 4; ++t) {
            float bn = gb1[n0 + t * 16 + c];
            gacc[t] = (f32x4){bn, bn, bn, bn};
        }
        #pragma unroll
        for (int kk = 0; kk < 4; ++kk) {
            bf16x8 av = *(const bf16x8*)&aggb[m0 + c][kk * 32 + q * 8];
            #pragma unroll
            for (int t = 0; t < 4; ++t) {
                bf16x8 bv = *(const bf16x8*)&wtg[(size_t)(n0 + t * 16 + c) * 128 + kk * 32 + q * 8];
                gacc[t] = __builtin_amdgcn_mfma_f32_16x16x32_bf16(av, bv, gacc[t], 0, 0, 0);
            }
        }
        float w2v[4];
        #pragma unroll
        for (int t = 0; t < 4; ++t) w2v[t] = gw2[n0 + t * 16 + c];
        float gs[4];
        #pragma unroll
        for (int r = 0; r < 4; ++r) {
            gs[r] = tanhf(gacc[0][r]) * w2v[0] + tanhf(gacc[1][r]) * w2v[1]
                  + tanhf(gacc[2][r]) * w2v[2] + tanhf(gacc[3][r]) * w2v[3];
        }
        #pragma unroll
        for (int o = 1; o <= 8; o <<= 1)
            #pragma unroll
            for (int r = 0; r < 4; ++r) gs[r] += __shfl_xor(gs[r], o);
        if (c == 0) {
            #pragma unroll
            for (int r = 0; r < 4; ++r) redg[nh][m0 + q * 4 + r] = gs[r];
        }
        __syncthreads();
        if ((wave & 1) == 0 && c == 0) {
            float bb2 = gb2[0];
            #pragma unroll
            for (int r = 0; r < 4; ++r) {
                int m = m0 + q * 4 + r;
                int n = nblk0 + m;
                float L = redg[0][m] + redg[1][m] + bb2;
                if (n < N_NODES) { logits[n] = L; lg[m] = L; }
                else lg[m] = -INFINITY;
            }
        }
        __syncthreads();
        if (wave == 0) {
            float l = (lane < GB) ? lg[lane] : -INFINITY;
            float mx = l;
            #pragma unroll
            for (int o = 32; o >= 1; o >>= 1) mx = fmaxf(mx, __shfl_xor(mx, o));
            float ex = (lane < GB && l > -INFINITY) ? expf(l - mx) : 0.f;
            #pragma unroll
            for (int o = 32; o >= 1; o >>= 1) ex += __shfl_xor(ex, o);
            if (lane == 0) gpart[blockIdx.x] = make_float2(mx, ex);
        }
    }
}

// ---------------- pool (stats folded in, 64-node chunks) / out ----------------

#define PC 64
__global__ __launch_bounds__(128) void gate_pool_v3(
        const unsigned short* __restrict__ h16, const float* __restrict__ logits,
        const float2* __restrict__ gpart, const int* __restrict__ batch,
        float* __restrict__ gate_out, float* __restrict__ pooled) {
    __shared__ float sb[4];
    __shared__ float gs[PC];
    __shared__ int bs[PC];
    int d = threadIdx.x;
    int lane = d & 63, wv = d >> 6;
    // global softmax stats from per-block partials (12.5 KB, L2-hot)
    float mx = -INFINITY;
    for (int i = d; i < NBLK; i += 128) mx = fmaxf(mx, gpart[i].x);
    #pragma unroll
    for (int o = 32; o >= 1; o >>= 1) mx = fmaxf(mx, __shfl_xor(mx, o));
    if (lane == 0) sb[wv] = mx;
    __syncthreads();
    mx = fmaxf(sb[0], sb[1]);
    float ssum = 0.f;
    for (int i = d; i < NBLK; i += 128) {
        float2 p = gpart[i];
        ssum += p.y * expf(p.x - mx);
    }
    #pragma unroll
    for (int o = 32; o >= 1; o >>= 1) ssum += __shfl_xor(ssum, o);
    if (lane == 0) sb[2 + wv] = ssum;
    __syncthreads();
    float inv = 1.0f / (sb[2] + sb[3]);

    int n0 = blockIdx.x * PC;
    if (d < PC) {
        int nj = n0 + d;
        if (nj < N_NODES) {
            float gv = expf(logits[nj] - mx) * inv;
            gs[d] = gv;
            bs[d] = batch[nj];
            gate_out[nj] = gv;
        }
    }
    __syncthreads();
    int count = min(PC, N_NODES - n0);
    float acc = 0.f;
    int cur = bs[0];
    int t = 0;
    for (; t + 3 < count; t += 4) {
        float h0 = bf2f(h16[(size_t)(n0 + t + 0) * D + d]);
        float h1 = bf2f(h16[(size_t)(n0 + t + 1) * D + d]);
        float h2 = bf2f(h16[(size_t)(n0 + t + 2) * D + d]);
        float h3 = bf2f(h16[(size_t)(n0 + t + 3) * D + d]);
        int b0 = bs[t], b1 = bs[t + 1], b2 = bs[t + 2], b3 = bs[t + 3];
        if (b0 != cur) { atomicAdd(&pooled[cur * D + d], acc); acc = 0.f; cur = b0; }
        acc = fmaf(h0, gs[t], acc);
        if (b1 != cur) { atomicAdd(&pooled[cur * D + d], acc); acc = 0.f; cur = b1; }
        acc = fmaf(h1, gs[t + 1], acc);
        if (b2 != cur) { atomicAdd(&pooled[cur * D + d], acc); acc = 0.f; cur = b2; }
        acc = fmaf(h2, gs[t + 2], acc);
        if (b3 != cur) { atomicAdd(&pooled[cur * D + d], acc); acc = 0.f; cur = b3; }
        acc = fmaf(h3, gs[t + 3], acc);
    }
    for (; t < count; ++t) {
        int bn = bs[t];
        if (bn != cur) { atomicAdd(&pooled[cur * D + d], acc); acc = 0.f; cur = bn; }
        acc = fmaf(bf2f(h16[(size_t)(n0 + t) * D + d]), gs[t], acc);
    }
    atomicAdd(&pooled[cur * D + d], acc);
}

__global__ void out_proj_kernel(const float* __restrict__ pooled, const float* __restrict__ w,
                                const float* __restrict__ b, const float* __restrict__ g,
                                const float* __restrict__ beta, float* __restrict__ emb) {
    __shared__ float ps[D];
    __shared__ float sbuf[2];
    int bg = blockIdx.x, d = threadIdx.x;
    ps[d] = pooled[bg * D + d];
    __syncthreads();
    float acc = b[d];
    #pragma unroll 8
    for (int k = 0; k < D; ++k) acc += ps[k] * w[k * D + d];
    float s = acc, q = acc * acc;
    #pragma unroll
    for (int o = 32; o >= 1; o >>= 1) { s += __shfl_down(s, o); q += __shfl_down(q, o); }
    if ((d & 63) == 0) { sbuf[d >> 6] = s; }
    __syncthreads();
    float fullsum = sbuf[0] + sbuf[1];
    __syncthreads();
    if ((d & 63) == 0) { sbuf[d >> 6] = q; }
    __syncthreads();
    float fullsq = sbuf[0] + sbuf[1];
    float m = fullsum * (1.0f / D);
    float var = fullsq * (1.0f / D) - m * m;
    float y = (acc - m) * rsqrtf(var + 1e-5f) * g[d] + beta[d];
    emb[bg * D + d] = gelu_exact(y);
}

extern "C" void kernel_launch(void* const* d_in, const int* in_sizes, int n_in,
                              void* d_out, int out_size, void* d_ws, size_t ws_size,
                              hipStream_t stream) {
    const float* x        = (const float*)d_in[0];
    const int*   edge     = (const int*)d_in[1];
    const int*   batch    = (const int*)d_in[2];
    const float* w_in     = (const float*)d_in[3];
    const float* b_in     = (const float*)d_in[4];
    const float* ln_in_g  = (const float*)d_in[5];
    const float* ln_in_b  = (const float*)d_in[6];
    const float* gnn_w    = (const float*)d_in[7];
    const float* gnn_b    = (const float*)d_in[8];
    const float* gnn_ln_g = (const float*)d_in[9];
    const float* gnn_ln_b = (const float*)d_in[10];
    const float* norm_g   = (const float*)d_in[11];
    const float* norm_b   = (const float*)d_in[12];
    const float* gate_w1  = (const float*)d_in[13];
    const float* gate_b1  = (const float*)d_in[14];
    const float* gate_w2  = (const float*)d_in[15];
    const float* gate_b2  = (const float*)d_in[16];
    const float* out_w    = (const float*)d_in[17];
    const float* out_b    = (const float*)d_in[18];
    const float* out_ln_g = (const float*)d_in[19];
    const float* out_ln_b = (const float*)d_in[20];

    const int* src = edge;             // edge_index[0]
    const int* dst = edge + N_EDGES;   // edge_index[1]

    float* out      = (float*)d_out;
    float* emb      = out;                               // (8,128)
    float* hA       = out + B_GRAPHS * D;                // (N,128) final h (fp32)
    float* gate_out = hA + (size_t)N_NODES * D;          // (N,)

    // workspace: bf16 ping-pong h16A/h16B; CSR temporaries deg/cursor overlaid in h16A
    unsigned short* h16A = (unsigned short*)d_ws;        // N*D bf16
    unsigned short* h16B = h16A + (size_t)N_NODES * D;   // N*D bf16
    int*   deg_i    = (int*)d_ws;                        // N      (overlay in h16A)
    int*   cursor   = (int*)d_ws + N_NODES;              // N+1    (overlay in h16A)
    int*   row_ptr  = (int*)(h16B + (size_t)N_NODES * D);// N+1
    int*   csr      = row_ptr + N_NODES + 1;             // E
    float* logits   = (float*)(csr + N_EDGES);           // N
    float* pooled   = logits + N_NODES;                  // 1024
    int*   partials = (int*)(pooled + B_GRAPHS * D);     // NPART
    float2* gpart   = (float2*)(((uintptr_t)(partials + NPART) + 15) & ~(uintptr_t)15); // NBLK
    unsigned short* wt  = (unsigned short*)(gpart + NBLK);
    unsigned short* wtg = wt + WT_GNN;                   // gate w1 bf16 [n=D][k=D]
    unsigned short* wti = wt + WT_G1;                    // w_in bf16 [n=D][k=F_IN]

    // CSR build + W prep (+pooled zero)
    hipMemsetAsync(deg_i, 0, N_NODES * sizeof(int), stream);
    degree_kernel<<<(N_EDGES + 255) / 256, 256, 0, stream>>>(dst, deg_i);
    scan_partials_kernel<<<NPART, SCAN_B, 0, stream>>>(deg_i, partials);
    scan_apply_v2<<<NPART, SCAN_B, 0, stream>>>(deg_i, partials, row_ptr, cursor);
    fill_kernel<<<(N_EDGES + 255) / 256, 256, 0, stream>>>(src, dst, cursor, csr);
    wprep_kernel<<<(WT_ALL + 255) / 256, 256, 0, stream>>>(gnn_w, gate_w1, w_in, wt, pooled);

    // input proj (MFMA) -> h16B
    input_proj_v5<<<NBLK, 256, 0, stream>>>(x, wti, b_in, ln_in_g, ln_in_b, h16B);

    // layers: h16B -> h16A -> h16B -> (h16A + hA fp32 + gate fused)
    gnn_layer_v8<0><<<NBLK, 256, 0, stream>>>(
        h16B, h16A, hA, csr, row_ptr, wt, gnn_b,
        gnn_ln_g, gnn_ln_b, norm_g, norm_b, 1, 0,
        nullptr, nullptr, nullptr, nullptr, nullptr, nullptr);
    gnn_layer_v8<0><<<NBLK, 256, 0, stream>>>(
        h16A, h16B, hA, csr, row_ptr, wt + (size_t)1 * D * 2 * D, gnn_b + D,
        gnn_ln_g + D, gnn_ln_b + D, norm_g + D, norm_b + D, 1, 0,
        nullptr, nullptr, nullptr, nullptr, nullptr, nullptr);
    gnn_layer_v8<1><<<NBLK, 256, 0, stream>>>(
        h16B, h16A, hA, csr, row_ptr, wt + (size_t)2 * D * 2 * D, gnn_b + 2 * D,
        gnn_ln_g + 2 * D, gnn_ln_b + 2 * D, norm_g + 2 * D, norm_b + 2 * D, 0, 1,
        wtg, gate_b1, gate_w2, gate_b2, logits, gpart);

    gate_pool_v3<<<(N_NODES + PC - 1) / PC, 128, 0, stream>>>(
        h16A, logits, gpart, batch, gate_out, pooled);
    out_proj_kernel<<<B_GRAPHS, D, 0, stream>>>(pooled, out_w, out_b, out_ln_g, out_ln_b, emb);
}